// Round 5
// baseline (165.467 us; speedup 1.0000x reference)
//
#include <hip/hip_runtime.h>
#include <math.h>

#define CB 2
#define CT 2048
#define CD 1024
#define CH 16
#define CHD 64
#define CWINDOW 512

typedef __bf16 bf16x8 __attribute__((ext_vector_type(8)));
typedef float floatx4 __attribute__((ext_vector_type(4)));

__device__ __forceinline__ unsigned short f2bf(float f) {
  union { float f; unsigned int u; } v;
  v.f = f;
  unsigned int u = v.u;
  u += 0x7fffu + ((u >> 16) & 1u);  // round-to-nearest-even
  return (unsigned short)(u >> 16);
}
__device__ __forceinline__ unsigned short f2bf_trunc(float f) {
  union { float f; unsigned int u; } v;
  v.f = f;
  return (unsigned short)(v.u >> 16);  // truncate (P>=0, consistent num/denom)
}
__device__ __forceinline__ float bf2f(unsigned int h) {
  union { unsigned int u; float f; } v;
  v.u = h << 16;
  return v.f;
}

// ---------------- fused convert: weights transpose->bf16 [N,K] + x->bf16 ----------------
// grid (16,16,12): z<4 -> weight tile (Wq,Wk,Wv,Wo); z>=4 -> x chunk.
__global__ __launch_bounds__(256) void cvt_all(const float* __restrict__ x,
                                               const float* __restrict__ Wq,
                                               const float* __restrict__ Wk,
                                               const float* __restrict__ Wv,
                                               const float* __restrict__ Wo,
                                               unsigned short* __restrict__ xb,
                                               unsigned short* __restrict__ WqT,
                                               unsigned short* __restrict__ WkT,
                                               unsigned short* __restrict__ WvT,
                                               unsigned short* __restrict__ WoT) {
  const int z = blockIdx.z;
  if (z < 4) {
    const float* W = z == 0 ? Wq : z == 1 ? Wk : z == 2 ? Wv : Wo;
    unsigned short* Wt = z == 0 ? WqT : z == 1 ? WkT : z == 2 ? WvT : WoT;
    __shared__ float tile[64][65];
    const int k0 = blockIdx.x * 64, n0 = blockIdx.y * 64;
    const int c = threadIdx.x & 63, r4 = threadIdx.x >> 6;
#pragma unroll
    for (int i = 0; i < 16; ++i) {
      int r = i * 4 + r4;
      tile[r][c] = W[(size_t)(k0 + r) * CD + n0 + c];
    }
    __syncthreads();
#pragma unroll
    for (int i = 0; i < 16; ++i) {
      int r = i * 4 + r4;
      Wt[(size_t)(n0 + r) * CD + k0 + c] = f2bf(tile[c][r]);
    }
  } else {
    const int idx = (z - 4) * 256 + blockIdx.y * 16 + blockIdx.x;
    const int i = idx * 256 + threadIdx.x;  // 8 floats per thread
    float4 a = ((const float4*)x)[i * 2];
    float4 b = ((const float4*)x)[i * 2 + 1];
    uint4 o;
    o.x = (unsigned int)f2bf(a.x) | ((unsigned int)f2bf(a.y) << 16);
    o.y = (unsigned int)f2bf(a.z) | ((unsigned int)f2bf(a.w) << 16);
    o.z = (unsigned int)f2bf(b.x) | ((unsigned int)f2bf(b.y) << 16);
    o.w = (unsigned int)f2bf(b.z) | ((unsigned int)f2bf(b.w) << 16);
    ((uint4*)xb)[i] = o;
  }
}

// ---------------- async 16B global -> LDS ----------------
__device__ __forceinline__ void async16(const unsigned short* g, unsigned short* l) {
  __builtin_amdgcn_global_load_lds(
      (const __attribute__((address_space(1))) unsigned int*)g,
      (__attribute__((address_space(3))) unsigned int*)l, 16, 0, 0);
}

// ---------------- GEMM fragment access: BK=32 tiles, 64B rows ----------------
// LDS(row, c_phys) holds global 16B chunk c_phys ^ (row&3) (source pre-swizzle
// (lane&3)^((lane>>2)&3) at stage). Read of logical chunk g=lane>>4 at row r
// uses phys = g ^ (r&3); spreads the 16 row-lanes to 4-way residual (1.58x)
// instead of 8-way at the naive 64B stride.
__device__ __forceinline__ bf16x8 frag32(const unsigned short* base, int row, int lane) {
  const int phys = ((lane >> 4) ^ (row & 3)) << 3;
  return *(const bf16x8*)&base[(row << 5) + phys];
}

// stage one BK=32 K-tile (t) of A[BM x 32] + B[128 x 32] into ring slot.
// Per wave: BM/64 + 2 global_load_lds instructions (4 for BM=128, 3 for BM=64).
template <int BM>
__device__ __forceinline__ void gemm_stage(const unsigned short* __restrict__ A,
                                           const unsigned short* __restrict__ Bt,
                                           unsigned short* __restrict__ As_s,
                                           unsigned short* __restrict__ Bs_s,
                                           int m0, int n0, int t, int wave, int lane) {
  const int row_in = lane >> 2;                          // 16 rows per slab
  const int src_c = ((lane & 3) ^ (row_in & 3)) * 8;     // pre-swizzled source chunk
  const int k0 = t * 32;
#pragma unroll
  for (int it = 0; it < BM / 64; ++it) {
    const int sub = wave * (BM / 64) + it;
    async16(A + (size_t)(m0 + sub * 16 + row_in) * CD + k0 + src_c, &As_s[sub * 512]);
  }
#pragma unroll
  for (int it = 0; it < 2; ++it) {
    const int sub = wave * 2 + it;
    async16(Bt + (size_t)(n0 + sub * 16 + row_in) * CD + k0 + src_c, &Bs_s[sub * 512]);
  }
}

// compute one K-tile: 8 ds_read_b128 + MT*4 MFMA (setprio-wrapped).
template <int MT>
__device__ __forceinline__ void gemm_compute(const unsigned short* __restrict__ As_s,
                                             const unsigned short* __restrict__ Bs_s,
                                             floatx4 (&acc)[MT][4], int mq, int nq, int lane) {
  const int fr = lane & 15;
  bf16x8 af[MT], bg[4];
#pragma unroll
  for (int mt = 0; mt < MT; ++mt) af[mt] = frag32(As_s, mq + mt * 16 + fr, lane);
#pragma unroll
  for (int nt = 0; nt < 4; ++nt) bg[nt] = frag32(Bs_s, nq + nt * 16 + fr, lane);
  __builtin_amdgcn_s_setprio(1);
#pragma unroll
  for (int mt = 0; mt < MT; ++mt)
#pragma unroll
    for (int nt = 0; nt < 4; ++nt)
      acc[mt][nt] = __builtin_amdgcn_mfma_f32_16x16x32_bf16(af[mt], bg[nt], acc[mt][nt], 0, 0, 0);
  __builtin_amdgcn_s_setprio(0);
}

// ---------------- bf16 MFMA GEMM: C[M,N] = A[M,K] @ Bt[N,K]^T ----------------
// BMx128 tile, BK=32, 3-slot LDS ring (48 KB for BM=128 -> 3 blocks/CU) with
// COUNTED vmcnt pipeline (T3+T4): per K-tile t: stage(t+2) -> ds_read(t) ->
// MFMA -> s_waitcnt vmcnt(STG) -> s_barrier. Proof: at end of phase t the
// wave's newest STG outstanding loads are exactly tile t+2's stages, so
// vmcnt(STG) guarantees tile t+1 landed BEFORE the barrier (cross-wave safe);
// the slot being staged was last read at phase t-1, barrier-sequenced. Main
// loop never drains vmcnt to 0 (the m97-structure's ~20% stall).
// MODE 0: C fp32 row-major [M,N].
// MODE 1: fused rmsnorm+rope epilogue, C bf16 [B,H,T,HD] in PERMUTED row layout:
//         stored pos 4c+j holds logical d = c+16j. Q and K share the
//         permutation -> QK^T invariant. Packed ushort4 stores.
// MODE 2: C bf16 scattered to [B,H,HD,T] (transposed V, canonical d), 8B stores.
template <int MODE, int BM>
__device__ __forceinline__ void mfma_gemm_body(const unsigned short* __restrict__ A,
                                               const unsigned short* __restrict__ Bt,
                                               void* __restrict__ Cout,
                                               const float* __restrict__ scale,
                                               float oscale, int m0, int n0,
                                               unsigned short* __restrict__ As,
                                               unsigned short* __restrict__ Bs) {
  constexpr int NT = CD / 32;     // 32 K-tiles
  constexpr int MT = BM / 32;     // m-tiles per wave
  constexpr int ASLOT = BM * 32;  // elems per A slot
  constexpr int BSLOT = 128 * 32;
  const int tid = threadIdx.x;
  const int wave = tid >> 6, lane = tid & 63;
  const int mq = (wave & 1) * (BM / 2), nq = (wave >> 1) * 64;

  floatx4 acc[MT][4] = {};

  // prologue: stage tiles 0,1; wait tile 0 landed (tile 1's stages stay in flight)
  gemm_stage<BM>(A, Bt, As, Bs, m0, n0, 0, wave, lane);
  gemm_stage<BM>(A, Bt, As + ASLOT, Bs + BSLOT, m0, n0, 1, wave, lane);
  if constexpr (BM == 128) asm volatile("s_waitcnt vmcnt(4)" ::: "memory");
  else asm volatile("s_waitcnt vmcnt(3)" ::: "memory");
  __builtin_amdgcn_s_barrier();

#pragma unroll 1
  for (int j = 0; j < (NT - 2) / 3; ++j) {  // 10 iters of 3 phases
#pragma unroll
    for (int u = 0; u < 3; ++u) {
      const int t = j * 3 + u;
      const int ss = (u + 2) % 3;  // stage slot (compile-time)
      gemm_stage<BM>(A, Bt, As + ss * ASLOT, Bs + ss * BSLOT, m0, n0, t + 2, wave, lane);
      gemm_compute<MT>(As + u * ASLOT, Bs + u * BSLOT, acc, mq, nq, lane);
      if constexpr (BM == 128) asm volatile("s_waitcnt vmcnt(4)" ::: "memory");
      else asm volatile("s_waitcnt vmcnt(3)" ::: "memory");
      __builtin_amdgcn_s_barrier();
    }
  }
  // epilogue tiles NT-2 (slot 0), NT-1 (slot 1): drain once, then finish
  gemm_compute<MT>(As + 0 * ASLOT, Bs + 0 * BSLOT, acc, mq, nq, lane);
  asm volatile("s_waitcnt vmcnt(0)" ::: "memory");
  __builtin_amdgcn_s_barrier();
  gemm_compute<MT>(As + 1 * ASLOT, Bs + 1 * BSLOT, acc, mq, nq, lane);

  // epilogue: C/D layout col=lane&15, row=(lane>>4)*4+i
  if (MODE == 1) {
    const int c = lane & 15;
    const int g = lane >> 4;
    const int hh = (n0 + nq) >> 6;  // head index (wave-uniform)
    const float kf = -0.2878231366242557f;  // -ln(10000)/32
    const float inv0 = __expf((float)c * kf);
    const float inv1 = __expf((float)(16 + c) * kf);
    float sc[4];
#pragma unroll
    for (int nt = 0; nt < 4; ++nt) sc[nt] = scale[nt * 16 + c];
#pragma unroll
    for (int mt = 0; mt < MT; ++mt) {
#pragma unroll
      for (int i = 0; i < 4; ++i) {
        const int m = m0 + mq + mt * 16 + g * 4 + i;
        const int b = m >> 11, t = m & (CT - 1);
        float v0 = acc[mt][0][i], v1 = acc[mt][1][i];
        float v2 = acc[mt][2][i], v3 = acc[mt][3][i];
        float ss = v0 * v0 + v1 * v1 + v2 * v2 + v3 * v3;
#pragma unroll
        for (int off = 8; off > 0; off >>= 1) ss += __shfl_xor(ss, off);
        const float rs = rsqrtf(ss * (1.0f / 64.0f) + 1e-6f);
        v0 *= rs * sc[0];
        v1 *= rs * sc[1];
        v2 *= rs * sc[2];
        v3 *= rs * sc[3];
        const float tf = (float)t;
        const float a0 = tf * inv0, a1 = tf * inv1;
        const float s0 = __sinf(a0), c0 = __cosf(a0);
        const float s1 = __sinf(a1), c1 = __cosf(a1);
        unsigned short* dst = (unsigned short*)Cout + ((size_t)(b * CH + hh) * CT + t) * CHD;
        ushort4 o;
        o.x = f2bf((v0 * c0 - v2 * s0) * oscale);  // logical d = c      -> pos 4c+0
        o.y = f2bf((v1 * c1 - v3 * s1) * oscale);  // logical d = 16+c   -> pos 4c+1
        o.z = f2bf((v2 * c0 + v0 * s0) * oscale);  // logical d = 32+c   -> pos 4c+2
        o.w = f2bf((v3 * c1 + v1 * s1) * oscale);  // logical d = 48+c   -> pos 4c+3
        *(ushort4*)&dst[4 * c] = o;
      }
    }
  } else {
#pragma unroll
    for (int mt = 0; mt < MT; ++mt) {
#pragma unroll
      for (int nt = 0; nt < 4; ++nt) {
        const int col = n0 + nq + nt * 16 + (lane & 15);
        if (MODE == 2) {
          const int mb = m0 + mq + mt * 16 + (lane >> 4) * 4;
          const int b = mb >> 11, t = mb & (CT - 1);
          const int h = col >> 6, d = col & 63;
          ushort4 o;
          o.x = f2bf(acc[mt][nt][0]);
          o.y = f2bf(acc[mt][nt][1]);
          o.z = f2bf(acc[mt][nt][2]);
          o.w = f2bf(acc[mt][nt][3]);
          *(ushort4*)&((unsigned short*)Cout)[((size_t)(b * CH + h) * CHD + d) * CT + t] = o;
        } else {
#pragma unroll
          for (int i = 0; i < 4; ++i) {
            const int m = m0 + mq + mt * 16 + (lane >> 4) * 4 + i;
            ((float*)Cout)[(size_t)m * CD + col] = acc[mt][nt][i];
          }
        }
      }
    }
  }
}

// z=0: Q (norm+rope, 0.125), z=1: K (norm+rope), z=2: V transposed.
// XCD 2D-chunked remap: XCD x = L%8 covers a FIXED 8-m-tile A-chunk
// (L2-resident) x 12 virtual weight panels; m cycles fast, panel slow.
// Bijective: 768 = 8 XCD * (8 m * 12 panels).
__global__ __launch_bounds__(256, 3) void gemm_qkv_mfma(const unsigned short* __restrict__ xb,
                                                        const unsigned short* __restrict__ WqT,
                                                        const unsigned short* __restrict__ WkT,
                                                        const unsigned short* __restrict__ WvT,
                                                        unsigned short* __restrict__ Qh,
                                                        unsigned short* __restrict__ Kh,
                                                        unsigned short* __restrict__ Vt,
                                                        const float* __restrict__ q_scale,
                                                        const float* __restrict__ k_scale) {
  __shared__ unsigned short As[3 * 128 * 32];  // 24 KB
  __shared__ unsigned short Bs[3 * 128 * 32];  // 24 KB
  const unsigned int L = blockIdx.x + 32u * blockIdx.y + 256u * blockIdx.z;
  const unsigned int x = L & 7u;        // XCD
  const unsigned int j = L >> 3;        // [0,96)
  const unsigned int gm = x & 3u;       // 4 A-groups (8 m-tiles each)
  const unsigned int gw = x >> 2;       // 2 W-groups (12 panels each)
  const unsigned int jm = j & 7u;       // fast axis: m within group
  const unsigned int jp = j >> 3;       // slow axis: panel within group [0,12)
  const int m0 = (int)(gm * 8u + jm) * 128;
  const unsigned int vp = gw * 12u + jp;  // virtual panel [0,24)
  const int n0 = (int)(vp & 7u) * 128;
  const int bz = (int)(vp >> 3);
  if (bz == 2) {
    mfma_gemm_body<2, 128>(xb, WvT, Vt, nullptr, 1.0f, m0, n0, As, Bs);
  } else if (bz == 0) {
    mfma_gemm_body<1, 128>(xb, WqT, Qh, q_scale, 0.125f, m0, n0, As, Bs);
  } else {
    mfma_gemm_body<1, 128>(xb, WkT, Kh, k_scale, 1.0f, m0, n0, As, Bs);
  }
}

// 64x128 tile -> 512 blocks (2/CU). Same ring pipeline (36 KB LDS, vmcnt(3)).
__global__ __launch_bounds__(256, 3) void gemm_out_mfma(const unsigned short* __restrict__ AO,
                                                        const unsigned short* __restrict__ WoT,
                                                        float* __restrict__ out) {
  __shared__ unsigned short As[3 * 64 * 32];   // 12 KB
  __shared__ unsigned short Bs[3 * 128 * 32];  // 24 KB
  const unsigned int L = blockIdx.x + 64u * blockIdx.y;  // [0,512)
  const unsigned int x = L & 7u;  // XCD
  const unsigned int j = L >> 3;  // [0,64)
  const unsigned int jm = j & 7u;
  const unsigned int jp = j >> 3;  // n-panel, slow
  const int m0 = (int)(x * 8u + jm) * 64;
  const int n0 = (int)jp * 128;
  mfma_gemm_body<0, 64>(AO, WoT, out, nullptr, 1.0f, m0, n0, As, Bs);
}

// ---------------- MFMA windowed attention with sink ----------------
// Grid (T/128, B*H) = 512 blocks -> 2/CU resident. 256 threads = 4 waves;
// wave w owns queries [q0+w*32, +32).
// 2-phase pipeline: K/V double-buffered, prefetch next tile first, ONE
// s_waitcnt vmcnt(0) + raw s_barrier per iter. XCD remap: each XCD serves
// 4 heads (bh = (L&7)*4 + L>>7) -> 2 MB K/V working set per XCD L2.
// Denominator via ones-row MFMA (lsacc): every lane holds its own q's sum.
__device__ __forceinline__ bf16x8 frag64(const unsigned short* base, int row, int ks, int lane) {
  const int phys = (((ks << 2) + (lane >> 4)) ^ (lane & 7)) << 3;
  return *(const bf16x8*)&base[(row << 6) + phys];
}

__global__ __launch_bounds__(256, 2) void attn_mfma(const unsigned short* __restrict__ Qh,
                                                    const unsigned short* __restrict__ Kh,
                                                    const unsigned short* __restrict__ Vt,
                                                    const float* __restrict__ sink_logit,
                                                    unsigned short* __restrict__ AO) {
  __shared__ unsigned short Qs[128 * 64];
  __shared__ unsigned short Ks[2][64 * 64];
  __shared__ unsigned short Vs[2][64 * 64];
  __shared__ unsigned short Ps[128 * 72];  // [q][s], stride 72

  const int tid = threadIdx.x;
  const int w = tid >> 6, lane = tid & 63;
  const unsigned int L = blockIdx.x + 16u * blockIdx.y;  // [0,512)
  const int qb = (int)((L >> 3) & 15u);
  const int bh = (int)(L & 7u) * 4 + (int)(L >> 7);
  const int b = bh >> 4, h = bh & 15;
  const int q0 = qb * 128;
  const unsigned short* Qb = Qh + (size_t)bh * CT * CHD;
  const unsigned short* Kb = Kh + (size_t)bh * CT * CHD;
  const unsigned short* Vb = Vt + (size_t)bh * CHD * CT;

  const int l7 = lane & 7, l8 = lane >> 3;
  const int sx8 = (l7 ^ l8) * 8;  // xor-swizzled source chunk

  const int kb_lo = (qb >= 4) ? (qb * 2 - 8) : 0;
  const int kb_hi = qb * 2 + 1;

  // ---- stage Q tile (128 rows) + first K/V tile into buf 0 ----
#pragma unroll
  for (int s = 0; s < 4; ++s) {
    const int slab = w * 4 + s;
    async16(Qb + (size_t)(q0 + slab * 8 + l8) * CHD + sx8, &Qs[slab * 512]);
  }
#pragma unroll
  for (int s = 0; s < 2; ++s) {
    const int slab = w * 2 + s;
    const int row = slab * 8 + l8;
    async16(Kb + (size_t)(kb_lo * 64 + row) * CHD + sx8, &Ks[0][slab * 512]);
    async16(Vb + (size_t)row * CT + kb_lo * 64 + sx8, &Vs[0][slab * 512]);
  }
  __syncthreads();

  bf16x8 qf[2][2];
#pragma unroll
  for (int nt = 0; nt < 2; ++nt)
#pragma unroll
    for (int ks = 0; ks < 2; ++ks)
      qf[nt][ks] = frag64(Qs, w * 32 + nt * 16 + (lane & 15), ks, lane);

  bf16x8 vones;
#pragma unroll
  for (int i = 0; i < 8; ++i) vones[i] = (__bf16)1.0f;

  floatx4 acc[4][2] = {};  // O^T tiles: [mt over d][nt over q]
  floatx4 lsacc[2] = {};   // denominator accumulator (ones-row MFMA)
  const int qw = q0 + w * 32;  // wave's first query

  int cur = 0;
  for (int kb = kb_lo; kb <= kb_hi; ++kb) {
    // ---- prefetch next K/V tile into the other buffer (overlaps compute) ----
    if (kb < kb_hi) {
#pragma unroll
      for (int s = 0; s < 2; ++s) {
        const int slab = w * 2 + s;
        const int row = slab * 8 + l8;
        async16(Kb + (size_t)((kb + 1) * 64 + row) * CHD + sx8, &Ks[cur ^ 1][slab * 512]);
        async16(Vb + (size_t)row * CT + (kb + 1) * 64 + sx8, &Vs[cur ^ 1][slab * 512]);
      }
    }

    const int kmin = kb * 64, kmax = kb * 64 + 63;
    if (!(kmin > qw + 31 || kmax <= qw - CWINDOW)) {  // not fully masked for this wave
      const unsigned short* Kc = Ks[cur];
      const unsigned short* Vc = Vs[cur];

      // ---- S^T = K · Q^T ----
      floatx4 st[4][2] = {};
#pragma unroll
      for (int ks = 0; ks < 2; ++ks) {
        bf16x8 kf[4];
#pragma unroll
        for (int mt = 0; mt < 4; ++mt)
          kf[mt] = frag64(Kc, mt * 16 + (lane & 15), ks, lane);
        __builtin_amdgcn_s_setprio(1);
#pragma unroll
        for (int mt = 0; mt < 4; ++mt)
#pragma unroll
          for (int nt = 0; nt < 2; ++nt)
            st[mt][nt] = __builtin_amdgcn_mfma_f32_16x16x32_bf16(kf[mt], qf[nt][ks], st[mt][nt], 0, 0, 0);
        __builtin_amdgcn_s_setprio(0);
      }

      // ---- P = exp(S), pack to LDS [q][s] ----
      const bool need_c = (kmax > qw);
      const bool need_w = (kmin <= qw + 31 - CWINDOW);
#pragma unroll
      for (int mt = 0; mt < 4; ++mt) {
#pragma unroll
        for (int nt = 0; nt < 2; ++nt) {
          const int s_base = kb * 64 + mt * 16 + (lane >> 4) * 4;
          const int t_g = q0 + w * 32 + nt * 16 + (lane & 15);
          ushort4 pk;
#pragma unroll
          for (int i = 0; i < 4; ++i) {
            float sv = st[mt][nt][i];
            if (need_c || need_w) {
              const int s_g = s_base + i;
              const bool ok = (!need_c || (s_g <= t_g)) && (!need_w || (s_g > t_g - CWINDOW));
              sv = ok ? sv : -INFINITY;
            }
            ((unsigned short*)&pk)[i] = f2bf_trunc(__expf(sv));
          }
          const int qrow = w * 32 + nt * 16 + (lane & 15);
          const int scol = mt * 16 + (lane >> 4) * 4;
          *(ushort4*)&Ps[qrow * 72 + scol] = pk;
        }
      }

      // ---- O^T += Vt · P ; denom += ones · P ----
#pragma unroll
      for (int ks = 0; ks < 2; ++ks) {
        bf16x8 vf[4], pf[2];
#pragma unroll
        for (int mt = 0; mt < 4; ++mt)
          vf[mt] = frag64(Vc, mt * 16 + (lane & 15), ks, lane);
#pragma unroll
        for (int nt = 0; nt < 2; ++nt) {
          const int qrow = w * 32 + nt * 16 + (lane & 15);
          pf[nt] = *(const bf16x8*)&Ps[qrow * 72 + ks * 32 + (lane >> 4) * 8];
        }
        __builtin_amdgcn_s_setprio(1);
#pragma unroll
        for (int mt = 0; mt < 4; ++mt)
#pragma unroll
          for (int nt = 0; nt < 2; ++nt)
            acc[mt][nt] = __builtin_amdgcn_mfma_f32_16x16x32_bf16(vf[mt], pf[nt], acc[mt][nt], 0, 0, 0);
#pragma unroll
        for (int nt = 0; nt < 2; ++nt)
          lsacc[nt] = __builtin_amdgcn_mfma_f32_16x16x32_bf16(vones, pf[nt], lsacc[nt], 0, 0, 0);
        __builtin_amdgcn_s_setprio(0);
      }
    }

    // ---- single barrier per iteration: own prefetch landed, then join ----
    asm volatile("s_waitcnt vmcnt(0)" ::: "memory");
    __builtin_amdgcn_s_barrier();
    cur ^= 1;
  }

  // ---- finalize: denominator (+ sink), normalize, store O ----
  const float sinkw = __expf(sink_logit[h]);
  float inv[2];
#pragma unroll
  for (int nt = 0; nt < 2; ++nt) inv[nt] = 1.0f / (lsacc[nt][0] + sinkw);
#pragma unroll
  for (int mt = 0; mt < 4; ++mt) {
#pragma unroll
    for (int nt = 0; nt < 2; ++nt) {
      const int t_g = q0 + w * 32 + nt * 16 + (lane & 15);
      const int d0 = mt * 16 + (lane >> 4) * 4;
      ushort4 o;
      o.x = f2bf(acc[mt][nt][0] * inv[nt]);
      o.y = f2bf(acc[mt][nt][1] * inv[nt]);
      o.z = f2bf(acc[mt][nt][2] * inv[nt]);
      o.w = f2bf(acc[mt][nt][3] * inv[nt]);
      *(ushort4*)&AO[(size_t)(b * CT + t_g) * CD + h * CHD + d0] = o;
    }
  }
}

extern "C" void kernel_launch(void* const* d_in, const int* in_sizes, int n_in,
                              void* d_out, int out_size, void* d_ws, size_t ws_size,
                              hipStream_t stream) {
  (void)in_sizes;
  (void)n_in;
  (void)out_size;
  (void)ws_size;
  const float* x = (const float*)d_in[0];
  const float* Wq = (const float*)d_in[1];
  const float* Wk = (const float*)d_in[2];
  const float* Wv = (const float*)d_in[3];
  const float* Wo = (const float*)d_in[4];
  const float* q_scale = (const float*)d_in[5];
  const float* k_scale = (const float*)d_in[6];
  const float* sink = (const float*)d_in[7];
  float* out = (float*)d_out;

  const size_t per = (size_t)CB * CH * CT * CHD;  // 4M elements
  unsigned short* Qh = (unsigned short*)d_ws;     // [B,H,T,HD] (permuted rows)
  unsigned short* Kh = Qh + per;                  // [B,H,T,HD] (permuted rows)
  unsigned short* Vt = Kh + per;                  // [B,H,HD,T]
  unsigned short* AO = Vt + per;                  // [B*T, D]
  unsigned short* xb = AO + per;                  // [B*T, D]
  unsigned short* WqT = xb + per;                 // [N,K] each
  unsigned short* WkT = WqT + (size_t)CD * CD;
  unsigned short* WvT = WkT + (size_t)CD * CD;
  unsigned short* WoT = WvT + (size_t)CD * CD;

  dim3 blk(256);
  cvt_all<<<dim3(16, 16, 12), blk, 0, stream>>>(x, Wq, Wk, Wv, Wo, xb, WqT, WkT, WvT, WoT);
  gemm_qkv_mfma<<<dim3(32, 8, 3), blk, 0, stream>>>(xb, WqT, WkT, WvT, Qh, Kh, Vt, q_scale, k_scale);
  attn_mfma<<<dim3(CT / 128, CB * CH), blk, 0, stream>>>(Qh, Kh, Vt, sink, AO);
  gemm_out_mfma<<<dim3(64, 8), blk, 0, stream>>>(AO, WoT, out);
}

// Round 6
// 156.425 us; speedup vs baseline: 1.0578x; 1.0578x over previous
//
#include <hip/hip_runtime.h>
#include <math.h>

#define CB 2
#define CT 2048
#define CD 1024
#define CH 16
#define CHD 64
#define CWINDOW 512

typedef __bf16 bf16x8 __attribute__((ext_vector_type(8)));
typedef float floatx4 __attribute__((ext_vector_type(4)));

__device__ __forceinline__ unsigned short f2bf(float f) {
  union { float f; unsigned int u; } v;
  v.f = f;
  unsigned int u = v.u;
  u += 0x7fffu + ((u >> 16) & 1u);  // round-to-nearest-even
  return (unsigned short)(u >> 16);
}
__device__ __forceinline__ unsigned short f2bf_trunc(float f) {
  union { float f; unsigned int u; } v;
  v.f = f;
  return (unsigned short)(v.u >> 16);  // truncate (P>=0, consistent num/denom)
}
__device__ __forceinline__ float bf2f(unsigned int h) {
  union { unsigned int u; float f; } v;
  v.u = h << 16;
  return v.f;
}

// ---------------- fused convert: weights transpose->bf16 [N,K] + x->bf16 ----------------
// grid (16,16,12): z<4 -> weight tile (Wq,Wk,Wv,Wo); z>=4 -> x chunk.
__global__ __launch_bounds__(256) void cvt_all(const float* __restrict__ x,
                                               const float* __restrict__ Wq,
                                               const float* __restrict__ Wk,
                                               const float* __restrict__ Wv,
                                               const float* __restrict__ Wo,
                                               unsigned short* __restrict__ xb,
                                               unsigned short* __restrict__ WqT,
                                               unsigned short* __restrict__ WkT,
                                               unsigned short* __restrict__ WvT,
                                               unsigned short* __restrict__ WoT) {
  const int z = blockIdx.z;
  if (z < 4) {
    const float* W = z == 0 ? Wq : z == 1 ? Wk : z == 2 ? Wv : Wo;
    unsigned short* Wt = z == 0 ? WqT : z == 1 ? WkT : z == 2 ? WvT : WoT;
    __shared__ float tile[64][65];
    const int k0 = blockIdx.x * 64, n0 = blockIdx.y * 64;
    const int c = threadIdx.x & 63, r4 = threadIdx.x >> 6;
#pragma unroll
    for (int i = 0; i < 16; ++i) {
      int r = i * 4 + r4;
      tile[r][c] = W[(size_t)(k0 + r) * CD + n0 + c];
    }
    __syncthreads();
#pragma unroll
    for (int i = 0; i < 16; ++i) {
      int r = i * 4 + r4;
      Wt[(size_t)(n0 + r) * CD + k0 + c] = f2bf(tile[c][r]);
    }
  } else {
    const int idx = (z - 4) * 256 + blockIdx.y * 16 + blockIdx.x;
    const int i = idx * 256 + threadIdx.x;  // 8 floats per thread
    float4 a = ((const float4*)x)[i * 2];
    float4 b = ((const float4*)x)[i * 2 + 1];
    uint4 o;
    o.x = (unsigned int)f2bf(a.x) | ((unsigned int)f2bf(a.y) << 16);
    o.y = (unsigned int)f2bf(a.z) | ((unsigned int)f2bf(a.w) << 16);
    o.z = (unsigned int)f2bf(b.x) | ((unsigned int)f2bf(b.y) << 16);
    o.w = (unsigned int)f2bf(b.z) | ((unsigned int)f2bf(b.w) << 16);
    ((uint4*)xb)[i] = o;
  }
}

// ---------------- async 16B global -> LDS ----------------
__device__ __forceinline__ void async16(const unsigned short* g, unsigned short* l) {
  __builtin_amdgcn_global_load_lds(
      (const __attribute__((address_space(1))) unsigned int*)g,
      (__attribute__((address_space(3))) unsigned int*)l, 16, 0, 0);
}

// XOR-swizzled fragment read from a [rows][64] bf16 LDS tile staged with the
// (l7^l8) source pre-swizzle: LDS(row, c_phys) holds global chunk c_phys^(row&7).
// Reading logical 16B chunk (ks*4 + lane>>4) of row r uses phys = chunk^(r&7);
// all call sites have (row&7) == (lane&7). Spreads the 16 row-lanes across 8
// bank-quads (2-way = free) instead of 16-way at the 128B row stride.
// (r5 lesson: BK=32's 64B rows only allow 4-way spread -> 3.1M conflicts; BK=64
// with this 8-way XOR is the conflict-free config.)
__device__ __forceinline__ bf16x8 frag64(const unsigned short* base, int row, int ks, int lane) {
  const int phys = (((ks << 2) + (lane >> 4)) ^ (lane & 7)) << 3;
  return *(const bf16x8*)&base[(row << 6) + phys];
}

// ---------------- bf16 MFMA GEMM: C[M,N] = A[M,K] @ Bt[N,K]^T ----------------
// BMx128 tile, BK=64, 32 KB LDS, XOR-swizzled, 2-barrier K-loop (r3-verified:
// 3 blocks/CU, conflict-free; r5's ring regressed -> reverted). 256 threads =
// 4 waves, 16 K-iterations x 32 MFMA. NEW (r6): staging pointers hoisted out
// of the K-loop and advanced by +128B/step — m98 asm showed ~21 v_lshl_add_u64
// per iter of redundant address recompute (VALUBusy ~24%).
// MODE 0: C fp32 row-major [M,N].
// MODE 1: fused rmsnorm+rope epilogue, C bf16 [B,H,T,HD] in PERMUTED row layout:
//         stored pos 4c+j holds logical d = c+16j. Q and K share the
//         permutation -> QK^T invariant. Packed ushort4 stores.
// MODE 2: C bf16 scattered to [B,H,HD,T] (transposed V, canonical d), 8B stores.
template <int MODE, int BM>
__device__ __forceinline__ void mfma_gemm_body(const unsigned short* __restrict__ A,
                                               const unsigned short* __restrict__ Bt,
                                               void* __restrict__ Cout,
                                               const float* __restrict__ scale,
                                               float oscale, int m0, int n0,
                                               unsigned short* __restrict__ As,
                                               unsigned short* __restrict__ Bs) {
  constexpr int K = CD;
  constexpr int MT = BM / 32;  // m-tiles per wave
  const int tid = threadIdx.x;
  const int wave = tid >> 6, lane = tid & 63;
  const int mq = (wave & 1) * (BM / 2), nq = (wave >> 1) * 64;

  floatx4 acc[MT][4] = {};
  const int l7 = lane & 7, l8 = lane >> 3;
  const int sxc = (l7 ^ l8) * 8;  // pre-swizzled source chunk (elements)
  const int fr = lane & 15;

  // hoisted staging pointers: one per async16, advanced +64 elems (128 B)/step
  const unsigned short* pa[BM / 32];
  const unsigned short* pb[4];
#pragma unroll
  for (int it = 0; it < BM / 32; ++it)
    pa[it] = A + (size_t)(m0 + (wave * (BM / 32) + it) * 8 + l8) * CD + sxc;
#pragma unroll
  for (int it = 0; it < 4; ++it)
    pb[it] = Bt + (size_t)(n0 + (wave * 4 + it) * 8 + l8) * CD + sxc;

  for (int k0 = 0; k0 < K; k0 += 64) {
    __syncthreads();
#pragma unroll
    for (int it = 0; it < BM / 32; ++it) {
      const int s = wave * (BM / 32) + it;
      async16(pa[it], &As[s * 512]);
      pa[it] += 64;
    }
#pragma unroll
    for (int it = 0; it < 4; ++it) {
      const int s = wave * 4 + it;
      async16(pb[it], &Bs[s * 512]);
      pb[it] += 64;
    }
    __syncthreads();
#pragma unroll
    for (int ks = 0; ks < 2; ++ks) {
      bf16x8 af[MT], bg[4];
#pragma unroll
      for (int mt = 0; mt < MT; ++mt)
        af[mt] = frag64(As, mq + mt * 16 + fr, ks, lane);
#pragma unroll
      for (int nt = 0; nt < 4; ++nt)
        bg[nt] = frag64(Bs, nq + nt * 16 + fr, ks, lane);
#pragma unroll
      for (int mt = 0; mt < MT; ++mt)
#pragma unroll
        for (int nt = 0; nt < 4; ++nt)
          acc[mt][nt] = __builtin_amdgcn_mfma_f32_16x16x32_bf16(af[mt], bg[nt], acc[mt][nt], 0, 0, 0);
    }
  }

  // epilogue: C/D layout col=lane&15, row=(lane>>4)*4+i
  if (MODE == 1) {
    const int c = lane & 15;
    const int g = lane >> 4;
    const int hh = (n0 + nq) >> 6;  // head index (wave-uniform)
    const float kf = -0.2878231366242557f;  // -ln(10000)/32
    const float inv0 = __expf((float)c * kf);
    const float inv1 = __expf((float)(16 + c) * kf);
    float sc[4];
#pragma unroll
    for (int nt = 0; nt < 4; ++nt) sc[nt] = scale[nt * 16 + c];
#pragma unroll
    for (int mt = 0; mt < MT; ++mt) {
#pragma unroll
      for (int i = 0; i < 4; ++i) {
        const int m = m0 + mq + mt * 16 + g * 4 + i;
        const int b = m >> 11, t = m & (CT - 1);
        float v0 = acc[mt][0][i], v1 = acc[mt][1][i];
        float v2 = acc[mt][2][i], v3 = acc[mt][3][i];
        float ss = v0 * v0 + v1 * v1 + v2 * v2 + v3 * v3;
#pragma unroll
        for (int off = 8; off > 0; off >>= 1) ss += __shfl_xor(ss, off);
        const float rs = rsqrtf(ss * (1.0f / 64.0f) + 1e-6f);
        v0 *= rs * sc[0];
        v1 *= rs * sc[1];
        v2 *= rs * sc[2];
        v3 *= rs * sc[3];
        const float tf = (float)t;
        const float a0 = tf * inv0, a1 = tf * inv1;
        const float s0 = __sinf(a0), c0 = __cosf(a0);
        const float s1 = __sinf(a1), c1 = __cosf(a1);
        unsigned short* dst = (unsigned short*)Cout + ((size_t)(b * CH + hh) * CT + t) * CHD;
        ushort4 o;
        o.x = f2bf((v0 * c0 - v2 * s0) * oscale);  // logical d = c      -> pos 4c+0
        o.y = f2bf((v1 * c1 - v3 * s1) * oscale);  // logical d = 16+c   -> pos 4c+1
        o.z = f2bf((v2 * c0 + v0 * s0) * oscale);  // logical d = 32+c   -> pos 4c+2
        o.w = f2bf((v3 * c1 + v1 * s1) * oscale);  // logical d = 48+c   -> pos 4c+3
        *(ushort4*)&dst[4 * c] = o;
      }
    }
  } else {
#pragma unroll
    for (int mt = 0; mt < MT; ++mt) {
#pragma unroll
      for (int nt = 0; nt < 4; ++nt) {
        const int col = n0 + nq + nt * 16 + (lane & 15);
        if (MODE == 2) {
          const int mb = m0 + mq + mt * 16 + (lane >> 4) * 4;
          const int b = mb >> 11, t = mb & (CT - 1);
          const int h = col >> 6, d = col & 63;
          ushort4 o;
          o.x = f2bf(acc[mt][nt][0]);
          o.y = f2bf(acc[mt][nt][1]);
          o.z = f2bf(acc[mt][nt][2]);
          o.w = f2bf(acc[mt][nt][3]);
          *(ushort4*)&((unsigned short*)Cout)[((size_t)(b * CH + h) * CHD + d) * CT + t] = o;
        } else {
#pragma unroll
          for (int i = 0; i < 4; ++i) {
            const int m = m0 + mq + mt * 16 + (lane >> 4) * 4 + i;
            ((float*)Cout)[(size_t)m * CD + col] = acc[mt][nt][i];
          }
        }
      }
    }
  }
}

// z=0: Q (norm+rope, 0.125), z=1: K (norm+rope), z=2: V transposed.
// XCD 2D-chunked remap (r5-verified: FETCH 68.8 -> 20.6 MB): XCD x = L%8
// covers a FIXED 8-m-tile A-chunk (L2-resident) x 12 virtual weight panels;
// m cycles fast, panel slow. Bijective: 768 = 8 XCD * (8 m * 12 panels).
__global__ __launch_bounds__(256, 3) void gemm_qkv_mfma(const unsigned short* __restrict__ xb,
                                                        const unsigned short* __restrict__ WqT,
                                                        const unsigned short* __restrict__ WkT,
                                                        const unsigned short* __restrict__ WvT,
                                                        unsigned short* __restrict__ Qh,
                                                        unsigned short* __restrict__ Kh,
                                                        unsigned short* __restrict__ Vt,
                                                        const float* __restrict__ q_scale,
                                                        const float* __restrict__ k_scale) {
  __shared__ unsigned short As[128 * 64];
  __shared__ unsigned short Bs[128 * 64];
  const unsigned int L = blockIdx.x + 32u * blockIdx.y + 256u * blockIdx.z;
  const unsigned int x = L & 7u;        // XCD
  const unsigned int j = L >> 3;        // [0,96)
  const unsigned int gm = x & 3u;       // 4 A-groups (8 m-tiles each)
  const unsigned int gw = x >> 2;       // 2 W-groups (12 panels each)
  const unsigned int jm = j & 7u;       // fast axis: m within group
  const unsigned int jp = j >> 3;       // slow axis: panel within group [0,12)
  const int m0 = (int)(gm * 8u + jm) * 128;
  const unsigned int vp = gw * 12u + jp;  // virtual panel [0,24)
  const int n0 = (int)(vp & 7u) * 128;
  const int bz = (int)(vp >> 3);
  if (bz == 2) {
    mfma_gemm_body<2, 128>(xb, WvT, Vt, nullptr, 1.0f, m0, n0, As, Bs);
  } else if (bz == 0) {
    mfma_gemm_body<1, 128>(xb, WqT, Qh, q_scale, 0.125f, m0, n0, As, Bs);
  } else {
    mfma_gemm_body<1, 128>(xb, WkT, Kh, k_scale, 1.0f, m0, n0, As, Bs);
  }
}

// 64x128 tile -> 512 blocks. XCD chunking: 8 m-tiles (1.05 MB AO chunk,
// L2-resident) per XCD, 8 WoT panels slow. 24 KB LDS.
__global__ __launch_bounds__(256, 3) void gemm_out_mfma(const unsigned short* __restrict__ AO,
                                                        const unsigned short* __restrict__ WoT,
                                                        float* __restrict__ out) {
  __shared__ unsigned short As[64 * 64];
  __shared__ unsigned short Bs[128 * 64];
  const unsigned int L = blockIdx.x + 64u * blockIdx.y;  // [0,512)
  const unsigned int x = L & 7u;  // XCD
  const unsigned int j = L >> 3;  // [0,64)
  const unsigned int jm = j & 7u;
  const unsigned int jp = j >> 3;  // n-panel, slow
  const int m0 = (int)(x * 8u + jm) * 64;
  const int n0 = (int)jp * 128;
  mfma_gemm_body<0, 64>(AO, WoT, out, nullptr, 1.0f, m0, n0, As, Bs);
}

// ---------------- MFMA windowed attention with sink ----------------
// Grid (T/128, B*H) = 512 blocks -> 2/CU resident. 256 threads = 4 waves;
// wave w owns queries [q0+w*32, +32).
// 2-phase pipeline: K/V double-buffered, prefetch next tile first, ONE
// s_waitcnt vmcnt(0) + raw s_barrier per iter. XCD remap: each XCD serves
// 4 heads (bh = (L&7)*4 + L>>7) -> 2 MB K/V working set per XCD L2.
// Denominator via ones-row MFMA (lsacc): every lane holds its own q's sum.
__global__ __launch_bounds__(256, 2) void attn_mfma(const unsigned short* __restrict__ Qh,
                                                    const unsigned short* __restrict__ Kh,
                                                    const unsigned short* __restrict__ Vt,
                                                    const float* __restrict__ sink_logit,
                                                    unsigned short* __restrict__ AO) {
  __shared__ unsigned short Qs[128 * 64];
  __shared__ unsigned short Ks[2][64 * 64];
  __shared__ unsigned short Vs[2][64 * 64];
  __shared__ unsigned short Ps[128 * 72];  // [q][s], stride 72

  const int tid = threadIdx.x;
  const int w = tid >> 6, lane = tid & 63;
  const unsigned int L = blockIdx.x + 16u * blockIdx.y;  // [0,512)
  const int qb = (int)((L >> 3) & 15u);
  const int bh = (int)(L & 7u) * 4 + (int)(L >> 7);
  const int b = bh >> 4, h = bh & 15;
  const int q0 = qb * 128;
  const unsigned short* Qb = Qh + (size_t)bh * CT * CHD;
  const unsigned short* Kb = Kh + (size_t)bh * CT * CHD;
  const unsigned short* Vb = Vt + (size_t)bh * CHD * CT;

  const int l7 = lane & 7, l8 = lane >> 3;
  const int sx8 = (l7 ^ l8) * 8;  // xor-swizzled source chunk

  const int kb_lo = (qb >= 4) ? (qb * 2 - 8) : 0;
  const int kb_hi = qb * 2 + 1;

  // ---- stage Q tile (128 rows) + first K/V tile into buf 0 ----
#pragma unroll
  for (int s = 0; s < 4; ++s) {
    const int slab = w * 4 + s;
    async16(Qb + (size_t)(q0 + slab * 8 + l8) * CHD + sx8, &Qs[slab * 512]);
  }
#pragma unroll
  for (int s = 0; s < 2; ++s) {
    const int slab = w * 2 + s;
    const int row = slab * 8 + l8;
    async16(Kb + (size_t)(kb_lo * 64 + row) * CHD + sx8, &Ks[0][slab * 512]);
    async16(Vb + (size_t)row * CT + kb_lo * 64 + sx8, &Vs[0][slab * 512]);
  }
  __syncthreads();

  bf16x8 qf[2][2];
#pragma unroll
  for (int nt = 0; nt < 2; ++nt)
#pragma unroll
    for (int ks = 0; ks < 2; ++ks)
      qf[nt][ks] = frag64(Qs, w * 32 + nt * 16 + (lane & 15), ks, lane);

  bf16x8 vones;
#pragma unroll
  for (int i = 0; i < 8; ++i) vones[i] = (__bf16)1.0f;

  floatx4 acc[4][2] = {};  // O^T tiles: [mt over d][nt over q]
  floatx4 lsacc[2] = {};   // denominator accumulator (ones-row MFMA)
  const int qw = q0 + w * 32;  // wave's first query

  int cur = 0;
  for (int kb = kb_lo; kb <= kb_hi; ++kb) {
    // ---- prefetch next K/V tile into the other buffer (overlaps compute) ----
    if (kb < kb_hi) {
#pragma unroll
      for (int s = 0; s < 2; ++s) {
        const int slab = w * 2 + s;
        const int row = slab * 8 + l8;
        async16(Kb + (size_t)((kb + 1) * 64 + row) * CHD + sx8, &Ks[cur ^ 1][slab * 512]);
        async16(Vb + (size_t)row * CT + (kb + 1) * 64 + sx8, &Vs[cur ^ 1][slab * 512]);
      }
    }

    const int kmin = kb * 64, kmax = kb * 64 + 63;
    if (!(kmin > qw + 31 || kmax <= qw - CWINDOW)) {  // not fully masked for this wave
      const unsigned short* Kc = Ks[cur];
      const unsigned short* Vc = Vs[cur];

      // ---- S^T = K · Q^T ----
      floatx4 st[4][2] = {};
#pragma unroll
      for (int ks = 0; ks < 2; ++ks) {
        bf16x8 kf[4];
#pragma unroll
        for (int mt = 0; mt < 4; ++mt)
          kf[mt] = frag64(Kc, mt * 16 + (lane & 15), ks, lane);
        __builtin_amdgcn_s_setprio(1);
#pragma unroll
        for (int mt = 0; mt < 4; ++mt)
#pragma unroll
          for (int nt = 0; nt < 2; ++nt)
            st[mt][nt] = __builtin_amdgcn_mfma_f32_16x16x32_bf16(kf[mt], qf[nt][ks], st[mt][nt], 0, 0, 0);
        __builtin_amdgcn_s_setprio(0);
      }

      // ---- P = exp(S), pack to LDS [q][s] ----
      const bool need_c = (kmax > qw);
      const bool need_w = (kmin <= qw + 31 - CWINDOW);
#pragma unroll
      for (int mt = 0; mt < 4; ++mt) {
#pragma unroll
        for (int nt = 0; nt < 2; ++nt) {
          const int s_base = kb * 64 + mt * 16 + (lane >> 4) * 4;
          const int t_g = q0 + w * 32 + nt * 16 + (lane & 15);
          ushort4 pk;
#pragma unroll
          for (int i = 0; i < 4; ++i) {
            float sv = st[mt][nt][i];
            if (need_c || need_w) {
              const int s_g = s_base + i;
              const bool ok = (!need_c || (s_g <= t_g)) && (!need_w || (s_g > t_g - CWINDOW));
              sv = ok ? sv : -INFINITY;
            }
            ((unsigned short*)&pk)[i] = f2bf_trunc(__expf(sv));
          }
          const int qrow = w * 32 + nt * 16 + (lane & 15);
          const int scol = mt * 16 + (lane >> 4) * 4;
          *(ushort4*)&Ps[qrow * 72 + scol] = pk;
        }
      }

      // ---- O^T += Vt · P ; denom += ones · P ----
#pragma unroll
      for (int ks = 0; ks < 2; ++ks) {
        bf16x8 vf[4], pf[2];
#pragma unroll
        for (int mt = 0; mt < 4; ++mt)
          vf[mt] = frag64(Vc, mt * 16 + (lane & 15), ks, lane);
#pragma unroll
        for (int nt = 0; nt < 2; ++nt) {
          const int qrow = w * 32 + nt * 16 + (lane & 15);
          pf[nt] = *(const bf16x8*)&Ps[qrow * 72 + ks * 32 + (lane >> 4) * 8];
        }
        __builtin_amdgcn_s_setprio(1);
#pragma unroll
        for (int mt = 0; mt < 4; ++mt)
#pragma unroll
          for (int nt = 0; nt < 2; ++nt)
            acc[mt][nt] = __builtin_amdgcn_mfma_f32_16x16x32_bf16(vf[mt], pf[nt], acc[mt][nt], 0, 0, 0);
#pragma unroll
        for (int nt = 0; nt < 2; ++nt)
          lsacc[nt] = __builtin_amdgcn_mfma_f32_16x16x32_bf16(vones, pf[nt], lsacc[nt], 0, 0, 0);
        __builtin_amdgcn_s_setprio(0);
      }
    }

    // ---- single barrier per iteration: own prefetch landed, then join ----
    asm volatile("s_waitcnt vmcnt(0)" ::: "memory");
    __builtin_amdgcn_s_barrier();
    cur ^= 1;
  }

  // ---- finalize: denominator (+ sink), normalize, store O ----
  const float sinkw = __expf(sink_logit[h]);
  float inv[2];
#pragma unroll
  for (int nt = 0; nt < 2; ++nt) inv[nt] = 1.0f / (lsacc[nt][0] + sinkw);
#pragma unroll
  for (int mt = 0; mt < 4; ++mt) {
#pragma unroll
    for (int nt = 0; nt < 2; ++nt) {
      const int t_g = q0 + w * 32 + nt * 16 + (lane & 15);
      const int d0 = mt * 16 + (lane >> 4) * 4;
      ushort4 o;
      o.x = f2bf(acc[mt][nt][0] * inv[nt]);
      o.y = f2bf(acc[mt][nt][1] * inv[nt]);
      o.z = f2bf(acc[mt][nt][2] * inv[nt]);
      o.w = f2bf(acc[mt][nt][3] * inv[nt]);
      *(ushort4*)&AO[(size_t)(b * CT + t_g) * CD + h * CHD + d0] = o;
    }
  }
}

extern "C" void kernel_launch(void* const* d_in, const int* in_sizes, int n_in,
                              void* d_out, int out_size, void* d_ws, size_t ws_size,
                              hipStream_t stream) {
  (void)in_sizes;
  (void)n_in;
  (void)out_size;
  (void)ws_size;
  const float* x = (const float*)d_in[0];
  const float* Wq = (const float*)d_in[1];
  const float* Wk = (const float*)d_in[2];
  const float* Wv = (const float*)d_in[3];
  const float* Wo = (const float*)d_in[4];
  const float* q_scale = (const float*)d_in[5];
  const float* k_scale = (const float*)d_in[6];
  const float* sink = (const float*)d_in[7];
  float* out = (float*)d_out;

  const size_t per = (size_t)CB * CH * CT * CHD;  // 4M elements
  unsigned short* Qh = (unsigned short*)d_ws;     // [B,H,T,HD] (permuted rows)
  unsigned short* Kh = Qh + per;                  // [B,H,T,HD] (permuted rows)
  unsigned short* Vt = Kh + per;                  // [B,H,HD,T]
  unsigned short* AO = Vt + per;                  // [B*T, D]
  unsigned short* xb = AO + per;                  // [B*T, D]
  unsigned short* WqT = xb + per;                 // [N,K] each
  unsigned short* WkT = WqT + (size_t)CD * CD;
  unsigned short* WvT = WkT + (size_t)CD * CD;
  unsigned short* WoT = WvT + (size_t)CD * CD;

  dim3 blk(256);
  cvt_all<<<dim3(16, 16, 12), blk, 0, stream>>>(x, Wq, Wk, Wv, Wo, xb, WqT, WkT, WvT, WoT);
  gemm_qkv_mfma<<<dim3(32, 8, 3), blk, 0, stream>>>(xb, WqT, WkT, WvT, Qh, Kh, Vt, q_scale, k_scale);
  attn_mfma<<<dim3(CT / 128, CB * CH), blk, 0, stream>>>(Qh, Kh, Vt, sink, AO);
  gemm_out_mfma<<<dim3(64, 8), blk, 0, stream>>>(AO, WoT, out);
}